// Round 9
// baseline (235.910 us; speedup 1.0000x reference)
//
#include <hip/hip_runtime.h>
#include <hip/hip_bf16.h>

// Problem: B=32, c_in=32, T=12, N=1024, ks=3, c_out=64
// R9: R7 structure + non-temporal hints:
//   - out stores NT (100MB stream was evicting L3-resident A/B panels;
//     FETCH 93.5MB vs ~32MB ideal = 3x overfetch evidence)
//   - prep reads x/Lk NT (dead after prep; keep xb/lbT cacheable for fused)

typedef __attribute__((ext_vector_type(8))) short s16x8;
typedef __attribute__((ext_vector_type(4))) float f32x4;
typedef __attribute__((ext_vector_type(4))) float fvec4;

__device__ __forceinline__ short f2bf(float f) {
    union { float f; unsigned u; } v; v.f = f;
    unsigned r = v.u + 0x7fffu + ((v.u >> 16) & 1u);   // RNE
    return (short)(r >> 16);
}
__device__ __forceinline__ float bf2f(short h) {
    union { unsigned u; float f; } v; v.u = ((unsigned)(unsigned short)h) << 16;
    return v.f;
}

// ---- fused prep: x->bf16, Lk->bf16 (n*3+k)-row-ordered, theta->bf16 [o][96]
#define U1 1572864   // x units (8 f32 each)
#define U2 393216    // lbT units (8 elems each)
#define U3 6144      // theta elems
__global__ __launch_bounds__(256) void prep_k(const float* __restrict__ x,
                                              const float* __restrict__ Lk,
                                              const float* __restrict__ th,
                                              short* __restrict__ xb,
                                              short* __restrict__ lbT,
                                              short* __restrict__ thb) {
    int gid = blockIdx.x * 256 + threadIdx.x;
    if (gid < U1) {
        const fvec4* s4 = (const fvec4*)x;
        fvec4 a = __builtin_nontemporal_load(&s4[2 * gid]);
        fvec4 b = __builtin_nontemporal_load(&s4[2 * gid + 1]);
        s16x8 o;
        o[0]=f2bf(a[0]); o[1]=f2bf(a[1]); o[2]=f2bf(a[2]); o[3]=f2bf(a[3]);
        o[4]=f2bf(b[0]); o[5]=f2bf(b[1]); o[6]=f2bf(b[2]); o[7]=f2bf(b[3]);
        ((s16x8*)xb)[gid] = o;
    } else if (gid < U1 + U2) {
        int u = gid - U1;
        int row = u >> 7, m8 = u & 127;       // row = n*3+k
        int n = row / 3, k = row - n * 3;
        const fvec4* s4 = (const fvec4*)(Lk + (k << 20) + n * 1024 + m8 * 8);
        fvec4 a = __builtin_nontemporal_load(&s4[0]);
        fvec4 b = __builtin_nontemporal_load(&s4[1]);
        s16x8 o;
        o[0]=f2bf(a[0]); o[1]=f2bf(a[1]); o[2]=f2bf(a[2]); o[3]=f2bf(a[3]);
        o[4]=f2bf(b[0]); o[5]=f2bf(b[1]); o[6]=f2bf(b[2]); o[7]=f2bf(b[3]);
        ((s16x8*)lbT)[row * 128 + m8] = o;
    } else if (gid < U1 + U2 + U3) {
        int e = gid - U1 - U2;                // theta (i,o,k): e = i*192+o*3+k
        int i = e / 192, rem = e - i * 192;
        int o = rem / 3, k = rem - o * 3;
        thb[o * 96 + i * 3 + k] = f2bf(th[e]);
    }
}

// ===== fused 8-phase GEMM + theta epilogue ===============================
// LDS (shorts): A ring 3 x 8192(=256x64) @0,16384,32768 ; B dbuf 2 x 12288
// (=192x64) @49152, 61440.  Total 73728 shorts = 144 KiB.
// T2 swizzle byte ^= ((row&7)<<4) via pre-swizzled global src + swz ds_read.
#define STAGE_A(kstep, j, ldsb)                                                 \
    __builtin_amdgcn_global_load_lds(                                           \
        (const __attribute__((address_space(1))) void*)                         \
            (A + a_srcoff[j] + (kstep) * 64),                                   \
        (__attribute__((address_space(3))) void*)                               \
            (&smem[(ldsb) + (j) * 4096 + w * 512]), 16, 0, 0);

#define STAGE_B(kstep, j, ldsb)                                                 \
    __builtin_amdgcn_global_load_lds(                                           \
        (const __attribute__((address_space(1))) void*)                         \
            (Bm + b_srcoff[j] + (kstep) * 64),                                  \
        (__attribute__((address_space(3))) void*)                               \
            (&smem[(ldsb) + (j) * 4096 + w * 512]), 16, 0, 0);

#define MFMA12(M0)                                                              \
    __builtin_amdgcn_s_setprio(1);                                              \
    _Pragma("unroll")                                                           \
    for (int mi = 0; mi < 2; ++mi) {                                            \
        _Pragma("unroll")                                                       \
        for (int ni = 0; ni < 3; ++ni) {                                        \
            acc[(M0) + mi][ni] = __builtin_amdgcn_mfma_f32_16x16x32_bf16(       \
                af[mi][0], bfm[ni][0], acc[(M0) + mi][ni], 0, 0, 0);            \
            acc[(M0) + mi][ni] = __builtin_amdgcn_mfma_f32_16x16x32_bf16(       \
                af[mi][1], bfm[ni][1], acc[(M0) + mi][ni], 0, 0, 0);            \
        }                                                                       \
    }                                                                           \
    __builtin_amdgcn_s_setprio(0);

#define WAIT_LGKM()                                                             \
    asm volatile("s_waitcnt lgkmcnt(0)" ::: "memory");                          \
    __builtin_amdgcn_sched_barrier(0);

__global__ __launch_bounds__(512, 2) void fused_k(const short* __restrict__ A,
                                                  const short* __restrict__ Bm,
                                                  const short* __restrict__ thb,
                                                  const float* __restrict__ bias,
                                                  float* __restrict__ out) {
    __shared__ short smem[73728];                 // 144 KiB
    const int tid  = threadIdx.x;
    const int lane = tid & 63;
    const int w    = tid >> 6;                    // 0..7
    const int wm   = w >> 2, wn = w & 3;          // 2 x 4 wave grid

    int bid = blockIdx.x;
    bid = (bid & 7) * 96 + (bid >> 3);            // T1 XCD swizzle (768%8==0)
    const int bm = bid >> 4, bn = bid & 15;       // 48 x 16 tiles
    const int g0 = bm * 8;                        // first (b,t) group

    // staging geometry (source pre-swizzled, LDS dest linear)
    const int srow8 = w * 8 + (lane >> 3);        // 0..63 within a quarter
    const int sj_c  = ((lane & 7) ^ (lane >> 3)) * 8;

    int a_srcoff[4];
    #pragma unroll
    for (int j = 0; j < 4; ++j) {
        const int q = j * 64 + srow8;             // local M row 0..255
        const int G = q >> 5, i = q & 31;
        const int g = g0 + G;
        const int b = g / 12, t_ = g - b * 12;
        a_srcoff[j] = (b * 384 + i * 12 + t_) * 1024 + sj_c;
    }
    int b_srcoff[3];
    #pragma unroll
    for (int j = 0; j < 3; ++j)
        b_srcoff[j] = (bn * 192 + j * 64 + srow8) * 1024 + sj_c;

    // swizzled ds_read col offsets (shorts)
    const int swzc0 = ((((lane >> 4) * 16)) ^ ((lane & 7) << 4)) >> 1;
    const int swzc1 = ((64 + (lane >> 4) * 16) ^ ((lane & 7) << 4)) >> 1;
    const int fr = lane & 15;

    f32x4 acc[8][3] = {};
    s16x8 bfm[3][2];

    // ---- prologue: A(0)->s0, B(0)->b0, A(1)->s1, B(1)->b1 ------------------
    STAGE_A(0, 0, 0)     STAGE_A(0, 1, 0)     STAGE_A(0, 2, 0)     STAGE_A(0, 3, 0)
    STAGE_B(0, 0, 49152) STAGE_B(0, 1, 49152) STAGE_B(0, 2, 49152)
    STAGE_A(1, 0, 16384) STAGE_A(1, 1, 16384) STAGE_A(1, 2, 16384) STAGE_A(1, 3, 16384)
    STAGE_B(1, 0, 61440) STAGE_B(1, 1, 61440) STAGE_B(1, 2, 61440)
    asm volatile("s_waitcnt vmcnt(7)" ::: "memory");   // A0,B0 landed; A1,B1 flying
    __builtin_amdgcn_s_barrier();

    int rs = 0, ss = 2;                           // read slot, stage slot (=rs+2 mod 3)
    for (int t = 0; t < 16; ++t) {
        const int abase = rs * 16384;
        const int astg  = ss * 16384;
        const int bbase = 49152 + (t & 1) * 12288;   // read & stage slot (WAR-safe)
        s16x8 af[2][2];

        // P0: B frags (6) + A m0,m1; stage A(t+2) q0,q1
        #pragma unroll
        for (int ni = 0; ni < 3; ++ni) {
            const int r = wn * 48 + ni * 16 + fr;
            bfm[ni][0] = *(const s16x8*)&smem[bbase + r * 64 + swzc0];
            bfm[ni][1] = *(const s16x8*)&smem[bbase + r * 64 + swzc1];
        }
        #pragma unroll
        for (int mi = 0; mi < 2; ++mi) {
            const int r = wm * 128 + mi * 16 + fr;
            af[mi][0] = *(const s16x8*)&smem[abase + r * 64 + swzc0];
            af[mi][1] = *(const s16x8*)&smem[abase + r * 64 + swzc1];
        }
        if (t < 14) { STAGE_A(t + 2, 0, astg) STAGE_A(t + 2, 1, astg) }
        __builtin_amdgcn_s_barrier();
        WAIT_LGKM();
        MFMA12(0);
        __builtin_amdgcn_s_barrier();

        // P1: A m2,m3; stage A(t+2) q2,q3
        #pragma unroll
        for (int mi = 0; mi < 2; ++mi) {
            const int r = wm * 128 + (mi + 2) * 16 + fr;
            af[mi][0] = *(const s16x8*)&smem[abase + r * 64 + swzc0];
            af[mi][1] = *(const s16x8*)&smem[abase + r * 64 + swzc1];
        }
        if (t < 14) { STAGE_A(t + 2, 2, astg) STAGE_A(t + 2, 3, astg) }
        __builtin_amdgcn_s_barrier();
        WAIT_LGKM();
        MFMA12(2);
        __builtin_amdgcn_s_barrier();

        // P2: A m4,m5; stage B(t+2) q0,q1
        #pragma unroll
        for (int mi = 0; mi < 2; ++mi) {
            const int r = wm * 128 + (mi + 4) * 16 + fr;
            af[mi][0] = *(const s16x8*)&smem[abase + r * 64 + swzc0];
            af[mi][1] = *(const s16x8*)&smem[abase + r * 64 + swzc1];
        }
        if (t < 14) { STAGE_B(t + 2, 0, bbase) STAGE_B(t + 2, 1, bbase) }
        __builtin_amdgcn_s_barrier();
        WAIT_LGKM();
        MFMA12(4);
        __builtin_amdgcn_s_barrier();

        // P3: A m6,m7; stage B(t+2) q2; boundary vmcnt
        #pragma unroll
        for (int mi = 0; mi < 2; ++mi) {
            const int r = wm * 128 + (mi + 6) * 16 + fr;
            af[mi][0] = *(const s16x8*)&smem[abase + r * 64 + swzc0];
            af[mi][1] = *(const s16x8*)&smem[abase + r * 64 + swzc1];
        }
        if (t < 14) { STAGE_B(t + 2, 2, bbase) }
        __builtin_amdgcn_s_barrier();
        WAIT_LGKM();
        MFMA12(6);
        if (t < 14) { asm volatile("s_waitcnt vmcnt(7)" ::: "memory"); }
        else        { asm volatile("s_waitcnt vmcnt(0)" ::: "memory"); }
        __builtin_amdgcn_s_barrier();
        rs = (rs == 2) ? 0 : rs + 1;
        ss = (ss == 2) ? 0 : ss + 1;
    }

    // ---- epilogue 1: acc -> LDS P^T[G][n_l][i*3+k], row stride 104 shorts ---
    const int rq = (lane >> 4) * 4;
    #pragma unroll
    for (int mi = 0; mi < 8; ++mi) {
        const int G = wm * 4 + (mi >> 1);
        const int ib = (mi & 1) * 16 + rq;
        #pragma unroll
        for (int ni = 0; ni < 3; ++ni) {
            const int c  = wn * 48 + ni * 16 + fr;   // = n_l*3 + k
            const int nl = c / 3, kk = c - nl * 3;
            const int base = G * 6656 + nl * 104 + kk;
            #pragma unroll
            for (int r = 0; r < 4; ++r)
                smem[base + (ib + r) * 3] = f2bf(acc[mi][ni][r]);
        }
    }
    __syncthreads();

    // ---- epilogue 2: per-wave theta-MFMA (64o x 64n, K=96) + writeout -------
    const int g  = g0 + w;
    const int b  = g / 12, t_ = g - b * 12;
    const int rq8 = (lane >> 4) * 8;
    s16x8 ta[4][3];
    #pragma unroll
    for (int oi = 0; oi < 4; ++oi)
        #pragma unroll
        for (int ks = 0; ks < 3; ++ks)
            ta[oi][ks] = *(const s16x8*)&thb[(oi * 16 + fr) * 96 + ks * 32 + rq8];

    f32x4 a2[4][4] = {};
    #pragma unroll
    for (int nj = 0; nj < 4; ++nj) {
        s16x8 pb[3];
        #pragma unroll
        for (int ks = 0; ks < 3; ++ks)
            pb[ks] = *(const s16x8*)&smem[w * 6656 + (nj * 16 + fr) * 104 + ks * 32 + rq8];
        #pragma unroll
        for (int oi = 0; oi < 4; ++oi)
            #pragma unroll
            for (int ks = 0; ks < 3; ++ks)
                a2[oi][nj] = __builtin_amdgcn_mfma_f32_16x16x32_bf16(
                    ta[oi][ks], pb[ks], a2[oi][nj], 0, 0, 0);
    }

    const int n0 = bn * 64;
    #pragma unroll
    for (int oi = 0; oi < 4; ++oi) {
        #pragma unroll
        for (int nj = 0; nj < 4; ++nj) {
            const int nl = n0 + nj * 16 + fr;
            #pragma unroll
            for (int r = 0; r < 4; ++r) {
                const int o = oi * 16 + rq + r;
                float v = a2[oi][nj][r] + bias[o];
                if (o < 32) v += bf2f(A[(b * 384 + o * 12 + t_) * 1024 + nl]);
                __builtin_nontemporal_store(fmaxf(v, 0.f),
                    &out[((b * 64 + o) * 12 + t_) * 1024 + nl]);
            }
        }
    }
}

extern "C" void kernel_launch(void* const* d_in, const int* in_sizes, int n_in,
                              void* d_out, int out_size, void* d_ws, size_t ws_size,
                              hipStream_t stream) {
    const float* x     = (const float*)d_in[0];
    const float* Lk    = (const float*)d_in[1];
    const float* theta = (const float*)d_in[2];
    const float* bias  = (const float*)d_in[3];
    float* out = (float*)d_out;

    char* ws = (char*)d_ws;
    short* xb  = (short*)(ws);                      // 25,165,824 B
    short* lbT = (short*)(ws + 25165824);           //  6,291,456 B
    short* thb = (short*)(ws + 31457280);           //     12,288 B

    hipLaunchKernelGGL(prep_k,  dim3(7704), dim3(256), 0, stream,
                       x, Lk, theta, xb, lbT, thb);
    hipLaunchKernelGGL(fused_k, dim3(768),  dim3(512), 0, stream,
                       xb, lbT, thb, bias, out);
}